// Round 3
// baseline (4738.207 us; speedup 1.0000x reference)
//
#include <hip/hip_runtime.h>
#include <hip/hip_fp16.h>
#include <math.h>

// ---------------------------------------------------------------------------
// RNN: h_{t+1} = relu(x_t @ W_in^T + h_t @ W_hh^T + b_hh + noise_t*scale)
// outputs: hidden_list [128,256,1024] f32, output_list [128,256,128] f32,
//          h_final [128,1024] f32 (concatenated flat in d_out)
//
// R3 design: BARRIER-FREE dataflow RNN.
//  - relu(h) >= 0  =>  fp16 sign bits of packed h words are always 0.
//    Bits 15/31 of each u32 carry a generation tag ((t>>1)&1). Consumers
//    spin-load until tag matches, strip, MFMA. No barriers, no flags,
//    no vmcnt(0), no __syncthreads in the whole time loop.
//  - 2-slot h ring: slot = t&1, tag = (t>>1)&1 disambiguates reuse.
//    Clobber-safety: slot s gen g+1 is written only after the writer consumed
//    all of gen g+1's inputs, which requires every wave of the group to have
//    finished reading gen g (all-to-all dependence). Race-free.
//  - B-fragments in REGISTERS (144 VGPR/lane, pre-transposed by setup into
//    per-lane order) -> no LDS -> 8 waves/block, 128 cols/block ->
//    8 blocks per batch-group (was 16).
//  - X transposed to t-major (contiguous 32KB per step, L2-friendly).
// ---------------------------------------------------------------------------

typedef _Float16 half8 __attribute__((ext_vector_type(8)));
typedef float    f32x4 __attribute__((ext_vector_type(4)));
typedef unsigned short ushort8 __attribute__((ext_vector_type(8)));
typedef unsigned long long u64;

#define SIGMA_F 0.05f

constexpr int T_  = 256;
constexpr int B_  = 128;
constexpr int NH  = 1024;
constexpr int NIN = 128;
constexpr int GM  = 8;     // batch groups (16 rows each)
constexpr int SL  = 8;     // column slices (128 cols each)
constexpr int MB  = 16;    // batch rows per group
constexpr int NCB = 128;   // cols per block
constexpr int NKC = 36;    // k-chunks of 32 (32 for h, 4 for x)

constexpr u64 TMASK = 0x8000800080008000ULL;
constexpr u64 DMASK = 0x7FFF7FFF7FFF7FFFULL;

// workspace layout (bytes), total ~12.6 MB
constexpr size_t OFF_XT = 0;                               // fp16 [T][B][NIN]  8.39MB
constexpr size_t OFF_NB = (size_t)T_*B_*NIN*2;             // f32  [T][NH]      1.05MB
constexpr size_t OFF_WO = OFF_NB + (size_t)T_*NH*4;        // fp16 [NIN][NH]    0.26MB
constexpr size_t OFF_WB = OFF_WO + (size_t)NIN*NH*2;       // fp16 b-frags      2.25MB
constexpr size_t OFF_HB = OFF_WB + (size_t)NH*(NH+NIN)*2;  // u32 [2][B][NH/2]  0.52MB

__device__ __forceinline__ unsigned short f16bits(float v) {
    return __half_as_ushort(__float2half(v));
}
__device__ __forceinline__ u64 ald(const u64* p) {
    return __hip_atomic_load(p, __ATOMIC_RELAXED, __HIP_MEMORY_SCOPE_AGENT);
}
__device__ __forceinline__ void ast(unsigned int* p, unsigned int v) {
    __hip_atomic_store(p, v, __ATOMIC_RELAXED, __HIP_MEMORY_SCOPE_AGENT);
}

// ---------------------------------------------------------------------------
__global__ void setup_kernel(const float* __restrict__ X,
                             const float* __restrict__ hidden,
                             const float* __restrict__ b_hh,
                             const float* __restrict__ W_in,
                             const float* __restrict__ W_hh,
                             const float* __restrict__ W_out,
                             const float* __restrict__ alpha_w,
                             const float* __restrict__ noise,
                             unsigned short* __restrict__ Xt,
                             float* __restrict__ NB,
                             unsigned short* __restrict__ Wo,
                             unsigned short* __restrict__ Wb,
                             unsigned int* __restrict__ Hb0,
                             unsigned int* __restrict__ Hb1)
{
    int idx = blockIdx.x * 256 + threadIdx.x;
    // X [B][T][NIN] -> Xt [T][B][NIN] fp16
    if (idx < B_ * T_ * NIN) {
        int d = idx & 127, rest = idx >> 7;
        int brow = rest & 127, t = rest >> 7;
        Xt[idx] = f16bits(X[((size_t)brow * T_ + t) * NIN + d]);
    }
    if (idx < T_ * NH) {
        int c = idx & (NH - 1);
        NB[idx] = b_hh[c] + noise[idx] * (sqrtf(2.0f / alpha_w[c]) * SIGMA_F);
    }
    if (idx < NIN * NH) Wo[idx] = f16bits(W_out[idx]);
    // Wb: per-(slice,wave,kchunk,lane) half8 b-fragments, lane-contiguous.
    // flat entry f: lane=f&63, ki=(f>>6)%36, nw=f/(64*36); row = nw*16+(lane&15)
    if (idx < NH * NKC * 64 / 64) { /* 1024/16*8? */ }
    if (idx < (GM * 0 + 512) * NKC * 64 && idx < 64 * NKC * 64 * 1) { }
    if (idx < 64 * NKC * 64) {   // 64 (slice,wave) pairs * 36 * 64 lanes = 147456
        int lane = idx & 63;
        int ki   = (idx >> 6) % NKC;
        int nw   = idx / (64 * NKC);
        int l15 = lane & 15, lk = lane >> 4;
        int row = nw * 16 + l15;                 // == n*128 + w*16 + l15
        unsigned short* dst = Wb + (size_t)idx * 8;
        if (ki < 32) {
            const float* s = W_hh + (size_t)row * NH + ki * 32 + lk * 8;
            #pragma unroll
            for (int j = 0; j < 8; ++j) dst[j] = f16bits(s[j]);
        } else {
            const float* s = W_in + (size_t)row * NIN + (ki - 32) * 32 + lk * 8;
            #pragma unroll
            for (int j = 0; j < 8; ++j) dst[j] = f16bits(s[j]);
        }
    }
    if (idx < B_ * NH / 2) {
        // slot0 = initial h (gen 0, tag 0); slot1 = poison (tag 1)
        unsigned int lo = f16bits(hidden[idx * 2]);
        unsigned int hi = f16bits(hidden[idx * 2 + 1]);
        Hb0[idx] = lo | (hi << 16);
        Hb1[idx] = 0x80008000u;
    }
}

// ---------------------------------------------------------------------------
// Barrier-free persistent RNN: 64 blocks x 512 threads (8 waves).
// Block (m = bx&7 batch-group, n = bx>>3 col-slice). Wave owns 16 cols.
__global__ __launch_bounds__(512, 1) void rnn_step_kernel(
    const unsigned short* __restrict__ Xt, const float* __restrict__ NB,
    const unsigned short* __restrict__ Wb,
    unsigned int* __restrict__ Hb0, unsigned int* __restrict__ Hb1,
    float* __restrict__ hidden_list, float* __restrict__ h_final)
{
    const int tid = threadIdx.x;
    const int wave = tid >> 6, lane = tid & 63;
    const int l15 = lane & 15, lk = lane >> 4;
    const int m = blockIdx.x & 7;    // batch group
    const int n = blockIdx.x >> 3;   // column slice
    const int rowA = m * MB + l15;
    const int gcol = n * NCB + wave * 16 + l15;

    // ---- preload B fragments into registers (36 x half8 = 144 VGPRs) ----
    half8 b[NKC];
    {
        const ushort8* wb = (const ushort8*)Wb + (size_t)(n * 8 + wave) * NKC * 64 + lane;
        #pragma unroll
        for (int ki = 0; ki < NKC; ++ki)
            b[ki] = __builtin_bit_cast(half8, wb[(size_t)ki * 64]);
    }

    auto xpart = [&](int t) -> f32x4 {
        f32x4 a = {0.f, 0.f, 0.f, 0.f};
        const ushort8* xp = (const ushort8*)(Xt + ((size_t)t * B_ + rowA) * NIN) + lk;
        #pragma unroll
        for (int ki = 0; ki < 4; ++ki) {
            half8 av = __builtin_bit_cast(half8, xp[ki * 4]);
            a = __builtin_amdgcn_mfma_f32_16x16x32_f16(av, b[32 + ki], a, 0, 0, 0);
        }
        return a;
    };

    f32x4 accx = xpart(0);

    for (int t = 0; t < T_; ++t) {
        const u64* hp = (const u64*)((t & 1) ? Hb1 : Hb0) + (size_t)rowA * 256 + lk * 2;
        const u64 expq = ((t >> 1) & 1) ? TMASK : 0ULL;
        f32x4 acc = accx;

        // ---- h contribution: 32 k-chunks, validated dataflow loads ----
        u64 qa[8], qb[8];
        #pragma unroll
        for (int j = 0; j < 4; ++j) {           // prologue: raw-load group 0
            qa[2*j]   = ald(hp + j * 8);
            qa[2*j+1] = ald(hp + j * 8 + 1);
        }
        #pragma unroll
        for (int g = 0; g < 8; ++g) {
            if (g < 7) {                        // prefetch next group
                #pragma unroll
                for (int j = 0; j < 4; ++j) {
                    int ki = (g + 1) * 4 + j;
                    qb[2*j]   = ald(hp + (size_t)ki * 8);
                    qb[2*j+1] = ald(hp + (size_t)ki * 8 + 1);
                }
            }
            #pragma unroll
            for (int j = 0; j < 4; ++j) {       // validate + strip + MFMA
                int ki = g * 4 + j;
                while ((((qa[2*j] ^ expq) | (qa[2*j+1] ^ expq)) & TMASK) != 0ULL) {
                    qa[2*j]   = ald(hp + (size_t)ki * 8);
                    qa[2*j+1] = ald(hp + (size_t)ki * 8 + 1);
                }
                union { u64 q[2]; half8 h; } u;
                u.q[0] = qa[2*j]   & DMASK;
                u.q[1] = qa[2*j+1] & DMASK;
                acc = __builtin_amdgcn_mfma_f32_16x16x32_f16(u.h, b[ki], acc, 0, 0, 0);
            }
            #pragma unroll
            for (int j = 0; j < 8; ++j) qa[j] = qb[j];
        }

        // ---- bias+noise, relu ----
        const float nb = NB[t * NH + gcol];
        float hv[4];
        #pragma unroll
        for (int r = 0; r < 4; ++r) {
            float v = acc[r] + nb;
            hv[r] = v > 0.f ? v : 0.f;
        }

        // ---- publish h_{t+1}: packed fp16 pair + generation tag ----
        if (t < T_ - 1) {
            unsigned int* hn = (t & 1) ? Hb0 : Hb1;
            const unsigned int tagb = (((t + 1) >> 1) & 1) ? 0x80008000u : 0u;
            #pragma unroll
            for (int r = 0; r < 4; ++r) {
                float other = __shfl_xor(hv[r], 1);
                if (!(lane & 1)) {
                    unsigned int val = (unsigned int)f16bits(hv[r]) |
                                       ((unsigned int)f16bits(other) << 16) | tagb;
                    int brow = m * MB + lk * 4 + r;
                    ast(&hn[(size_t)brow * 512 + (gcol >> 1)], val);
                }
            }
        }

        // ---- fp32 outputs (off critical path) ----
        #pragma unroll
        for (int r = 0; r < 4; ++r) {
            int brow = m * MB + lk * 4 + r;
            hidden_list[((size_t)brow * T_ + t) * NH + gcol] = hv[r];
        }
        if (t == T_ - 1) {
            #pragma unroll
            for (int r = 0; r < 4; ++r) {
                int brow = m * MB + lk * 4 + r;
                h_final[(size_t)brow * NH + gcol] = hv[r];
            }
        } else {
            accx = xpart(t + 1);
        }
    }
}

// ---------------------------------------------------------------------------
// Readout: Y[32768,128] = HL[32768,1024](f32->f16) @ Wo^T(f16), fp32 out.
__global__ __launch_bounds__(256, 4) void ygemm_kernel(
    const float* __restrict__ HL, const unsigned short* __restrict__ Wo,
    float* __restrict__ Y)
{
    const int tid = threadIdx.x;
    const int wave = tid >> 6, lane = tid & 63;
    const int l15 = lane & 15, lk = lane >> 4;
    const size_t rowbase = (size_t)blockIdx.x * 64;

    f32x4 acc[4][2] = {};

    #pragma unroll 2
    for (int ki = 0; ki < 32; ++ki) {
        const int k0 = ki * 32 + lk * 8;
        half8 bfr[2];
        #pragma unroll
        for (int nt = 0; nt < 2; ++nt) {
            int ncol = (wave * 2 + nt) * 16 + l15;
            ushort8 braw = *(const ushort8*)(Wo + ncol * NH + k0);
            bfr[nt] = __builtin_bit_cast(half8, braw);
        }
        #pragma unroll
        for (int mt = 0; mt < 4; ++mt) {
            size_t row = rowbase + mt * 16 + l15;
            const float4* ap = (const float4*)(HL + row * NH + k0);
            float4 a0 = ap[0];
            float4 a1 = ap[1];
            half8 a = { (_Float16)a0.x, (_Float16)a0.y, (_Float16)a0.z, (_Float16)a0.w,
                        (_Float16)a1.x, (_Float16)a1.y, (_Float16)a1.z, (_Float16)a1.w };
            #pragma unroll
            for (int nt = 0; nt < 2; ++nt)
                acc[mt][nt] = __builtin_amdgcn_mfma_f32_16x16x32_f16(a, bfr[nt], acc[mt][nt], 0, 0, 0);
        }
    }

    #pragma unroll
    for (int mt = 0; mt < 4; ++mt) {
        #pragma unroll
        for (int nt = 0; nt < 2; ++nt) {
            int ncol = (wave * 2 + nt) * 16 + l15;
            #pragma unroll
            for (int r = 0; r < 4; ++r) {
                size_t row = rowbase + mt * 16 + lk * 4 + r;
                Y[row * NIN + ncol] = acc[mt][nt][r];
            }
        }
    }
}

// ---------------------------------------------------------------------------
extern "C" void kernel_launch(void* const* d_in, const int* in_sizes, int n_in,
                              void* d_out, int out_size, void* d_ws, size_t ws_size,
                              hipStream_t stream)
{
    const float* X      = (const float*)d_in[0];  // [128,256,128]
    const float* hidden = (const float*)d_in[1];  // [128,1024]
    const float* W_in   = (const float*)d_in[2];  // [1024,128]
    const float* W_hh   = (const float*)d_in[3];  // [1024,1024]
    const float* b_hh   = (const float*)d_in[4];  // [1024]
    const float* W_out  = (const float*)d_in[5];  // [128,1024]
    const float* alpha  = (const float*)d_in[6];  // [1024]
    const float* noise  = (const float*)d_in[7];  // [256,1024]

    char* ws = (char*)d_ws;   // ~12.6 MB
    unsigned short* Xt = (unsigned short*)(ws + OFF_XT);
    float*          NB = (float*)(ws + OFF_NB);
    unsigned short* Wo = (unsigned short*)(ws + OFF_WO);
    unsigned short* Wb = (unsigned short*)(ws + OFF_WB);
    unsigned int*  Hb0 = (unsigned int*)(ws + OFF_HB);
    unsigned int*  Hb1 = Hb0 + (size_t)B_ * NH / 2;

    float* hidden_list = (float*)d_out;                                  // [128,256,1024]
    float* output_list = hidden_list + (size_t)B_ * T_ * NH;             // [128,256,128]
    float* h_final     = output_list + (size_t)B_ * T_ * NIN;            // [128,1024]

    setup_kernel<<<(B_ * T_ * NIN + 255) / 256, 256, 0, stream>>>(
        X, hidden, b_hh, W_in, W_hh, W_out, alpha, noise,
        Xt, NB, Wo, Wb, Hb0, Hb1);

    rnn_step_kernel<<<GM * SL, 512, 0, stream>>>(
        Xt, NB, Wb, Hb0, Hb1, hidden_list, h_final);

    ygemm_kernel<<<(B_ * T_) / 64, 256, 0, stream>>>(
        hidden_list, Wo, output_list);
}

// Round 4
// 3512.378 us; speedup vs baseline: 1.3490x; 1.3490x over previous
//
#include <hip/hip_runtime.h>
#include <hip/hip_fp16.h>
#include <math.h>

// ---------------------------------------------------------------------------
// RNN: h_{t+1} = relu(x_t @ W_in^T + h_t @ W_hh^T + b_hh + noise_t*scale)
// outputs: hidden_list [128,256,1024] f32, output_list [128,256,128] f32,
//          h_final [128,1024] f32 (concatenated flat in d_out)
//
// R4: barrier-free dataflow (tag-in-data) + LDS-resident W + BATCHED retry.
//  - relu(h) >= 0 => fp16 sign bits of packed h are 0; bits15/31 of each u32
//    carry generation tag ((t>>1)&1). Consumers validate tags, strip, MFMA.
//    No barriers / flags / vmcnt / __syncthreads in the time loop.
//  - R3 failure: eager loads returned stale tags -> per-word SERIAL reloads
//    (~64 x 600cyc = 16us/step). Fix: validate groups of 16 u64 with an
//    AND/OR tree and reload the whole group in PARALLEL (1 RT per round).
//  - R3 failure 2: b-frags in regs (144 VGPR) got spilled by compiler.
//    Fix: W stays in LDS (R2 layout, 64 cols x 1152, 148KB, 1 block/CU).
//  - 2-slot h ring: slot=t&1, tag=(t>>1)&1. Clobber-safe by all-to-all dep.
//  - X kept t-major (R3's FETCH_SIZE win: 300MB -> 74MB).
// ---------------------------------------------------------------------------

typedef _Float16 half8 __attribute__((ext_vector_type(8)));
typedef float    f32x4 __attribute__((ext_vector_type(4)));
typedef unsigned short ushort8 __attribute__((ext_vector_type(8)));
typedef unsigned long long u64;

#define SIGMA_F 0.05f

constexpr int T_  = 256;
constexpr int B_  = 128;
constexpr int NH  = 1024;
constexpr int NIN = 128;
constexpr int KC  = NH + NIN;     // 1152
constexpr int GM  = 8;            // batch groups (16 rows each)
constexpr int GN  = 16;           // column slices (64 cols each)
constexpr int MB  = 16;
constexpr int NSUB = 64;          // cols per block
constexpr int WROW = KC + 8;      // padded LDS row (halves), 16B-aligned rows

constexpr u64 TMASK = 0x8000800080008000ULL;
constexpr u64 DMASK = 0x7FFF7FFF7FFF7FFFULL;

// workspace layout (bytes)
constexpr size_t OFF_XT  = 0;                            // fp16 [T][B][NIN] 8.39MB
constexpr size_t OFF_NB  = (size_t)T_*B_*NIN*2;          // f32  [T][NH]     1.05MB
constexpr size_t OFF_WO  = OFF_NB + (size_t)T_*NH*4;     // fp16 [NIN][NH]   0.26MB
constexpr size_t OFF_HB  = OFF_WO + (size_t)NIN*NH*2;    // u32 [2][B][NH/2] 0.52MB

__device__ __forceinline__ unsigned short f16bits(float v) {
    return __half_as_ushort(__float2half(v));
}
__device__ __forceinline__ u64 ald(const u64* p) {
    return __hip_atomic_load(p, __ATOMIC_RELAXED, __HIP_MEMORY_SCOPE_AGENT);
}
__device__ __forceinline__ void ast(unsigned int* p, unsigned int v) {
    __hip_atomic_store(p, v, __ATOMIC_RELAXED, __HIP_MEMORY_SCOPE_AGENT);
}

// ---------------------------------------------------------------------------
__global__ void setup_kernel(const float* __restrict__ X,
                             const float* __restrict__ hidden,
                             const float* __restrict__ b_hh,
                             const float* __restrict__ W_out,
                             const float* __restrict__ alpha_w,
                             const float* __restrict__ noise,
                             unsigned short* __restrict__ Xt,
                             float* __restrict__ NB,
                             unsigned short* __restrict__ Wo,
                             unsigned int* __restrict__ Hb0,
                             unsigned int* __restrict__ Hb1)
{
    int idx = blockIdx.x * 256 + threadIdx.x;
    // X [B][T][NIN] -> Xt [T][B][NIN] fp16
    if (idx < B_ * T_ * NIN) {
        int d = idx & 127, rest = idx >> 7;
        int brow = rest & 127, t = rest >> 7;
        Xt[idx] = f16bits(X[((size_t)brow * T_ + t) * NIN + d]);
    }
    if (idx < T_ * NH) {
        int c = idx & (NH - 1);
        NB[idx] = b_hh[c] + noise[idx] * (sqrtf(2.0f / alpha_w[c]) * SIGMA_F);
    }
    if (idx < NIN * NH) Wo[idx] = f16bits(W_out[idx]);
    if (idx < B_ * NH / 2) {
        // slot0 = initial h, gen-0 tag (sign bits stripped; init h is zeros);
        // slot1 = poison with tag 1
        unsigned int lo = f16bits(hidden[idx * 2]);
        unsigned int hi = f16bits(hidden[idx * 2 + 1]);
        Hb0[idx] = (lo | (hi << 16)) & 0x7FFF7FFFu;
        Hb1[idx] = 0x80008000u;
    }
}

// ---------------------------------------------------------------------------
// Barrier-free persistent RNN: 128 blocks x 256 threads (4 waves, 1 block/CU).
// Block (m = bx/GN batch-group, n = bx%GN col-slice). Wave owns 16 cols.
__global__ __launch_bounds__(256, 1) void rnn_step_kernel(
    const float* __restrict__ W_hh, const float* __restrict__ W_in,
    const unsigned short* __restrict__ Xt, const float* __restrict__ NB,
    unsigned int* __restrict__ Hb0, unsigned int* __restrict__ Hb1,
    float* __restrict__ hidden_list, float* __restrict__ h_final)
{
    __shared__ _Float16 wlds[NSUB * WROW];   // 64 x 1160 fp16 = 148,480 B

    const int tid = threadIdx.x;
    const int m = blockIdx.x / GN;
    const int n = blockIdx.x % GN;

    // Stage W slice: local row nl = local col, K = [W_hh | W_in]
    for (int idx = tid; idx < NSUB * KC; idx += 256) {
        int nl = idx / KC, k = idx - nl * KC;
        int gc = n * NSUB + nl;
        float v = (k < NH) ? W_hh[gc * NH + k] : W_in[gc * NIN + (k - NH)];
        wlds[nl * WROW + k] = (_Float16)v;
    }
    __syncthreads();

    const int wave = tid >> 6, lane = tid & 63;
    const int l15 = lane & 15, lk = lane >> 4;
    const int rowA = m * MB + l15;          // batch row (A-frag row)
    const int colW = wave * 16 + l15;       // local col (B-frag row)
    const int gcol = n * NSUB + colW;       // global hidden col
    const int wbase = colW * WROW;

    auto xpart = [&](int t) -> f32x4 {
        f32x4 a = {0.f, 0.f, 0.f, 0.f};
        const ushort8* xp = (const ushort8*)(Xt + ((size_t)t * B_ + rowA) * NIN) + lk;
        #pragma unroll
        for (int ki = 0; ki < 4; ++ki) {
            half8 av = __builtin_bit_cast(half8, xp[ki * 4]);
            half8 bv = *(const half8*)&wlds[wbase + NH + ki * 32 + lk * 8];
            a = __builtin_amdgcn_mfma_f32_16x16x32_f16(av, bv, a, 0, 0, 0);
        }
        return a;
    };

    f32x4 accx = xpart(0);

    for (int t = 0; t < T_; ++t) {
        const u64* hp = (const u64*)((t & 1) ? Hb1 : Hb0) + (size_t)rowA * 256 + lk * 2;
        const bool tagset = ((t >> 1) & 1) != 0;
        const float nb = NB[t * NH + gcol];
        f32x4 acc = accx;

        // ---- issue ALL 64 h-word loads (32 chunks x 2 u64), pipelined ----
        u64 q[64];
        #pragma unroll
        for (int ki = 0; ki < 32; ++ki) {
            q[2*ki]   = ald(hp + (size_t)ki * 8);
            q[2*ki+1] = ald(hp + (size_t)ki * 8 + 1);
        }

        // ---- 4 groups of 8 chunks: batch-validate, batch-reload, MFMA ----
        #pragma unroll
        for (int g = 0; g < 4; ++g) {
            // validate 16 u64 via AND/OR tree; on failure reload ALL 16 in
            // parallel (one L3 round trip per retry round, not 16 serial)
            for (;;) {
                u64 red;
                if (tagset) {
                    red = q[16*g];
                    #pragma unroll
                    for (int j = 1; j < 16; ++j) red &= q[16*g + j];
                    red = ~red;
                } else {
                    red = q[16*g];
                    #pragma unroll
                    for (int j = 1; j < 16; ++j) red |= q[16*g + j];
                }
                if ((red & TMASK) == 0ULL) break;
                #pragma unroll
                for (int j = 0; j < 8; ++j) {
                    int ki = g * 8 + j;
                    q[2*ki]   = ald(hp + (size_t)ki * 8);
                    q[2*ki+1] = ald(hp + (size_t)ki * 8 + 1);
                }
            }
            #pragma unroll
            for (int j = 0; j < 8; ++j) {
                int ki = g * 8 + j;
                union { u64 w[2]; half8 h; } u;
                u.w[0] = q[2*ki]   & DMASK;
                u.w[1] = q[2*ki+1] & DMASK;
                half8 bv = *(const half8*)&wlds[wbase + ki * 32 + lk * 8];
                acc = __builtin_amdgcn_mfma_f32_16x16x32_f16(u.h, bv, acc, 0, 0, 0);
            }
        }

        // ---- bias+noise, relu ----
        float hv[4];
        #pragma unroll
        for (int r = 0; r < 4; ++r) {
            float v = acc[r] + nb;
            hv[r] = v > 0.f ? v : 0.f;
        }

        // ---- publish h_{t+1} FIRST (tagged, fire-and-forget sc1) ----
        if (t < T_ - 1) {
            unsigned int* hn = (t & 1) ? Hb0 : Hb1;
            const unsigned int tagb = (((t + 1) >> 1) & 1) ? 0x80008000u : 0u;
            #pragma unroll
            for (int r = 0; r < 4; ++r) {
                float other = __shfl_xor(hv[r], 1);
                if (!(lane & 1)) {
                    unsigned int val = (unsigned int)f16bits(hv[r]) |
                                       ((unsigned int)f16bits(other) << 16) | tagb;
                    int brow = m * MB + lk * 4 + r;
                    ast(&hn[(size_t)brow * 512 + (gcol >> 1)], val);
                }
            }
        }

        // ---- off-critical-path: fp32 outputs, next x-part ----
        #pragma unroll
        for (int r = 0; r < 4; ++r) {
            int brow = m * MB + lk * 4 + r;
            hidden_list[((size_t)brow * T_ + t) * NH + gcol] = hv[r];
        }
        if (t == T_ - 1) {
            #pragma unroll
            for (int r = 0; r < 4; ++r) {
                int brow = m * MB + lk * 4 + r;
                h_final[(size_t)brow * NH + gcol] = hv[r];
            }
        } else {
            accx = xpart(t + 1);
        }
    }
}

// ---------------------------------------------------------------------------
// Readout: Y[32768,128] = HL[32768,1024](f32->f16) @ Wo^T(f16), fp32 out.
__global__ __launch_bounds__(256, 4) void ygemm_kernel(
    const float* __restrict__ HL, const unsigned short* __restrict__ Wo,
    float* __restrict__ Y)
{
    const int tid = threadIdx.x;
    const int wave = tid >> 6, lane = tid & 63;
    const int l15 = lane & 15, lk = lane >> 4;
    const size_t rowbase = (size_t)blockIdx.x * 64;

    f32x4 acc[4][2] = {};

    #pragma unroll 2
    for (int ki = 0; ki < 32; ++ki) {
        const int k0 = ki * 32 + lk * 8;
        half8 bfr[2];
        #pragma unroll
        for (int nt = 0; nt < 2; ++nt) {
            int ncol = (wave * 2 + nt) * 16 + l15;
            ushort8 braw = *(const ushort8*)(Wo + ncol * NH + k0);
            bfr[nt] = __builtin_bit_cast(half8, braw);
        }
        #pragma unroll
        for (int mt = 0; mt < 4; ++mt) {
            size_t row = rowbase + mt * 16 + l15;
            const float4* ap = (const float4*)(HL + row * NH + k0);
            float4 a0 = ap[0];
            float4 a1 = ap[1];
            half8 a = { (_Float16)a0.x, (_Float16)a0.y, (_Float16)a0.z, (_Float16)a0.w,
                        (_Float16)a1.x, (_Float16)a1.y, (_Float16)a1.z, (_Float16)a1.w };
            #pragma unroll
            for (int nt = 0; nt < 2; ++nt)
                acc[mt][nt] = __builtin_amdgcn_mfma_f32_16x16x32_f16(a, bfr[nt], acc[mt][nt], 0, 0, 0);
        }
    }

    #pragma unroll
    for (int mt = 0; mt < 4; ++mt) {
        #pragma unroll
        for (int nt = 0; nt < 2; ++nt) {
            int ncol = (wave * 2 + nt) * 16 + l15;
            #pragma unroll
            for (int r = 0; r < 4; ++r) {
                size_t row = rowbase + mt * 16 + lk * 4 + r;
                Y[row * NIN + ncol] = acc[mt][nt][r];
            }
        }
    }
}

// ---------------------------------------------------------------------------
extern "C" void kernel_launch(void* const* d_in, const int* in_sizes, int n_in,
                              void* d_out, int out_size, void* d_ws, size_t ws_size,
                              hipStream_t stream)
{
    const float* X      = (const float*)d_in[0];
    const float* hidden = (const float*)d_in[1];
    const float* W_in   = (const float*)d_in[2];
    const float* W_hh   = (const float*)d_in[3];
    const float* b_hh   = (const float*)d_in[4];
    const float* W_out  = (const float*)d_in[5];
    const float* alpha  = (const float*)d_in[6];
    const float* noise  = (const float*)d_in[7];

    char* ws = (char*)d_ws;   // ~10.2 MB
    unsigned short* Xt = (unsigned short*)(ws + OFF_XT);
    float*          NB = (float*)(ws + OFF_NB);
    unsigned short* Wo = (unsigned short*)(ws + OFF_WO);
    unsigned int*  Hb0 = (unsigned int*)(ws + OFF_HB);
    unsigned int*  Hb1 = Hb0 + (size_t)B_ * NH / 2;

    float* hidden_list = (float*)d_out;                                  // [128,256,1024]
    float* output_list = hidden_list + (size_t)B_ * T_ * NH;             // [128,256,128]
    float* h_final     = output_list + (size_t)B_ * T_ * NIN;            // [128,1024]

    setup_kernel<<<(B_ * T_ * NIN + 255) / 256, 256, 0, stream>>>(
        X, hidden, b_hh, W_out, alpha, noise, Xt, NB, Wo, Hb0, Hb1);

    rnn_step_kernel<<<GM * GN, 256, 0, stream>>>(
        W_hh, W_in, Xt, NB, Hb0, Hb1, hidden_list, h_final);

    ygemm_kernel<<<(B_ * T_) / 64, 256, 0, stream>>>(
        hidden_list, Wo, output_list);
}

// Round 5
// 841.645 us; speedup vs baseline: 5.6297x; 4.1732x over previous
//
#include <hip/hip_runtime.h>
#include <hip/hip_fp16.h>
#include <math.h>

// ---------------------------------------------------------------------------
// RNN: h_{t+1} = relu(x_t @ W_in^T + h_t @ W_hh^T + b_hh + noise_t*scale)
// outputs: hidden_list [128,256,1024] f32, output_list [128,256,128] f32,
//          h_final [128,1024] f32 (concatenated flat in d_out)
//
// R5: barrier-free tag-in-data + COOPERATIVE LDS h-staging + backoff.
//  - Tag scheme (proven R3/R4): relu(h)>=0 => fp16 sign bits free; bits 15/31
//    of each packed u32 carry generation tag ((t>>1)&1). 2-slot ring.
//  - R4 failures fixed: (a) h loaded ONCE per block (256 thr x 128B) into an
//    LDS h-tile (was 4x redundant per-wave loads); (b) spin retries are one
//    batched 16-u64 round + s_sleep(2) backoff (was unthrottled flood);
//    (c) VGPR budget bounded (q[16]=32 VGPR, not q[64]=128).
//  - LDS: W chunks 0..29 (64x960 fp16, XOR-swizzled granules, no pad) 120KB
//    + h-tile (16x1024 fp16, same swizzle) 32KB = 152KB. W chunks 30,31 and
//    the 4 x-part chunks live in per-lane registers (24 VGPR).
//  - Swizzle phi(row,G): 16B-granule G -> G ^ (row&7). Conflict-free b128
//    reads (rows spread over 8 bank-clusters), bijective per row.
// ---------------------------------------------------------------------------

typedef _Float16 half8 __attribute__((ext_vector_type(8)));
typedef float    f32x4 __attribute__((ext_vector_type(4)));
typedef unsigned short ushort8 __attribute__((ext_vector_type(8)));
typedef unsigned long long u64;

#define SIGMA_F 0.05f

constexpr int T_  = 256;
constexpr int B_  = 128;
constexpr int NH  = 1024;
constexpr int NIN = 128;
constexpr int GM  = 8;            // batch groups (16 rows each)
constexpr int GN  = 16;           // column slices (64 cols each)
constexpr int MB  = 16;

constexpr u64 TMASK = 0x8000800080008000ULL;
constexpr u64 DMASK = 0x7FFF7FFF7FFF7FFFULL;

// workspace layout (bytes)
constexpr size_t OFF_XT  = 0;                            // fp16 [T][B][NIN] 8.39MB
constexpr size_t OFF_NB  = (size_t)T_*B_*NIN*2;          // f32  [T][NH]     1.05MB
constexpr size_t OFF_WO  = OFF_NB + (size_t)T_*NH*4;     // fp16 [NIN][NH]   0.26MB
constexpr size_t OFF_HB  = OFF_WO + (size_t)NIN*NH*2;    // u32 [2][B][512]  0.52MB

__device__ __forceinline__ unsigned short f16bits(float v) {
    return __half_as_ushort(__float2half(v));
}
__device__ __forceinline__ u64 ald(const u64* p) {
    return __hip_atomic_load(p, __ATOMIC_RELAXED, __HIP_MEMORY_SCOPE_AGENT);
}
__device__ __forceinline__ void ast(unsigned int* p, unsigned int v) {
    __hip_atomic_store(p, v, __ATOMIC_RELAXED, __HIP_MEMORY_SCOPE_AGENT);
}

// ---------------------------------------------------------------------------
__global__ void setup_kernel(const float* __restrict__ X,
                             const float* __restrict__ hidden,
                             const float* __restrict__ b_hh,
                             const float* __restrict__ W_out,
                             const float* __restrict__ alpha_w,
                             const float* __restrict__ noise,
                             unsigned short* __restrict__ Xt,
                             float* __restrict__ NB,
                             unsigned short* __restrict__ Wo,
                             unsigned int* __restrict__ Hb0,
                             unsigned int* __restrict__ Hb1)
{
    int idx = blockIdx.x * 256 + threadIdx.x;
    // X [B][T][NIN] -> Xt [T][B][NIN] fp16
    if (idx < B_ * T_ * NIN) {
        int d = idx & 127, rest = idx >> 7;
        int brow = rest & 127, t = rest >> 7;
        Xt[idx] = f16bits(X[((size_t)brow * T_ + t) * NIN + d]);
    }
    if (idx < T_ * NH) {
        int c = idx & (NH - 1);
        NB[idx] = b_hh[c] + noise[idx] * (sqrtf(2.0f / alpha_w[c]) * SIGMA_F);
    }
    if (idx < NIN * NH) Wo[idx] = f16bits(W_out[idx]);
    if (idx < B_ * NH / 2) {
        // slot0 = initial h with gen-0 tag (0); slot1 = poison (tag 1)
        unsigned int lo = f16bits(hidden[idx * 2]);
        unsigned int hi = f16bits(hidden[idx * 2 + 1]);
        Hb0[idx] = (lo | (hi << 16)) & 0x7FFF7FFFu;
        Hb1[idx] = 0x80008000u;
    }
}

// ---------------------------------------------------------------------------
// Barrier-free persistent RNN: 128 blocks x 256 threads (4 waves, 1 block/CU).
__global__ __launch_bounds__(256, 1) void rnn_step_kernel(
    const float* __restrict__ W_hh, const float* __restrict__ W_in,
    const unsigned short* __restrict__ Xt, const float* __restrict__ NB,
    unsigned int* __restrict__ Hb0, unsigned int* __restrict__ Hb1,
    float* __restrict__ hidden_list, float* __restrict__ h_final)
{
    __shared__ unsigned short wtile[64 * 960];    // 122,880 B (chunks 0..29)
    __shared__ unsigned short htile[16 * 1024];   //  32,768 B (full h tile)

    const int tid = threadIdx.x;
    const int m = blockIdx.x / GN;   // batch group
    const int n = blockIdx.x % GN;   // column slice

    const int wave = tid >> 6, lane = tid & 63;
    const int l15 = lane & 15, lk = lane >> 4;
    const int rowA = m * MB + l15;          // batch row (A-frag)
    const int colW = wave * 16 + l15;       // local W row / output col
    const int gcol = n * 64 + colW;         // global hidden col

    // ---- stage W chunks 0..29 into LDS (swizzled granules) ----
    for (int g = tid; g < 64 * 120; g += 256) {
        int row = g / 120, G = g - row * 120;
        const float* s = W_hh + (size_t)(n * 64 + row) * NH + G * 8;
        half8 h;
        #pragma unroll
        for (int j = 0; j < 8; ++j) h[j] = (_Float16)s[j];
        *(half8*)&wtile[row * 960 + ((G ^ (row & 7)) << 3)] = h;
    }

    // ---- per-lane register B-fragments: W_hh chunks 30,31 + W_in 4 chunks ----
    auto cvt8 = [](const float* s) {
        half8 h;
        #pragma unroll
        for (int j = 0; j < 8; ++j) h[j] = (_Float16)s[j];
        return h;
    };
    half8 bh30 = cvt8(W_hh + (size_t)gcol * NH + 960 + lk * 8);
    half8 bh31 = cvt8(W_hh + (size_t)gcol * NH + 992 + lk * 8);
    half8 bx[4];
    #pragma unroll
    for (int kx = 0; kx < 4; ++kx)
        bx[kx] = cvt8(W_in + (size_t)gcol * NIN + kx * 32 + lk * 8);
    __syncthreads();

    // h staging role: thread -> (row, part); 8 granules G = j*16+part
    const int hrow = tid >> 4;       // 0..15
    const int part = tid & 15;

    auto xpart = [&](int t) -> f32x4 {
        f32x4 a = {0.f, 0.f, 0.f, 0.f};
        const ushort8* xp = (const ushort8*)(Xt + ((size_t)t * B_ + rowA) * NIN) + lk;
        #pragma unroll
        for (int kx = 0; kx < 4; ++kx) {
            half8 av = __builtin_bit_cast(half8, xp[kx * 4]);
            a = __builtin_amdgcn_mfma_f32_16x16x32_f16(av, bx[kx], a, 0, 0, 0);
        }
        return a;
    };

    f32x4 accx = xpart(0);

    for (int t = 0; t < T_; ++t) {
        // ---- phase 1: cooperative tagged load of group h (128B/thread) ----
        const u64* hp = (const u64*)((t & 1) ? Hb1 : Hb0)
                        + (size_t)(m * MB + hrow) * 256 + part * 2;
        const u64 expq = ((t >> 1) & 1) ? TMASK : 0ULL;
        u64 q[16];
        for (;;) {
            #pragma unroll
            for (int j = 0; j < 8; ++j) {
                q[2*j]   = ald(hp + j * 32);
                q[2*j+1] = ald(hp + j * 32 + 1);
            }
            u64 red = 0;
            #pragma unroll
            for (int i = 0; i < 16; ++i) red |= q[i] ^ expq;
            if ((red & TMASK) == 0ULL) break;
            __builtin_amdgcn_s_sleep(2);   // polite backoff, avoid L3 flood
        }

        __syncthreads();   // prior-iteration htile reads complete

        // strip tags, stage to LDS (swizzled granules)
        #pragma unroll
        for (int j = 0; j < 8; ++j) {
            union { u64 w[2]; half8 h; } u;
            u.w[0] = q[2*j]   & DMASK;
            u.w[1] = q[2*j+1] & DMASK;
            int G = j * 16 + part;
            *(half8*)&htile[hrow * 1024 + ((G ^ (hrow & 7)) << 3)] = u.h;
        }

        __syncthreads();   // htile ready

        // ---- phase 2: 36 MFMAs (30 LDS-B + 2 reg-B + 4 x already in accx) ----
        f32x4 acc = accx;
        #pragma unroll
        for (int ki = 0; ki < 30; ++ki) {
            int G = 4 * ki + lk;
            half8 av = *(const half8*)&htile[l15 * 1024 + ((G ^ (l15 & 7)) << 3)];
            half8 bv = *(const half8*)&wtile[colW * 960 + ((G ^ (colW & 7)) << 3)];
            acc = __builtin_amdgcn_mfma_f32_16x16x32_f16(av, bv, acc, 0, 0, 0);
        }
        {
            int G = 120 + lk;
            half8 av = *(const half8*)&htile[l15 * 1024 + ((G ^ (l15 & 7)) << 3)];
            acc = __builtin_amdgcn_mfma_f32_16x16x32_f16(av, bh30, acc, 0, 0, 0);
            G = 124 + lk;
            av = *(const half8*)&htile[l15 * 1024 + ((G ^ (l15 & 7)) << 3)];
            acc = __builtin_amdgcn_mfma_f32_16x16x32_f16(av, bh31, acc, 0, 0, 0);
        }

        // ---- bias+noise, relu ----
        const float nb = NB[t * NH + gcol];
        float hv[4];
        #pragma unroll
        for (int r = 0; r < 4; ++r) {
            float v = acc[r] + nb;
            hv[r] = v > 0.f ? v : 0.f;
        }

        // ---- publish h_{t+1} FIRST (tag carried in-word, fire-and-forget) ----
        if (t < T_ - 1) {
            unsigned int* hn = (t & 1) ? Hb0 : Hb1;
            const unsigned int tagb = (((t + 1) >> 1) & 1) ? 0x80008000u : 0u;
            #pragma unroll
            for (int r = 0; r < 4; ++r) {
                float other = __shfl_xor(hv[r], 1);
                if (!(lane & 1)) {
                    unsigned int val = (unsigned int)f16bits(hv[r]) |
                                       ((unsigned int)f16bits(other) << 16) | tagb;
                    int brow = m * MB + lk * 4 + r;
                    ast(&hn[(size_t)brow * 512 + (gcol >> 1)], val);
                }
            }
        }

        // ---- off-critical-path: fp32 outputs, next x-part ----
        #pragma unroll
        for (int r = 0; r < 4; ++r) {
            int brow = m * MB + lk * 4 + r;
            hidden_list[((size_t)brow * T_ + t) * NH + gcol] = hv[r];
        }
        if (t == T_ - 1) {
            #pragma unroll
            for (int r = 0; r < 4; ++r) {
                int brow = m * MB + lk * 4 + r;
                h_final[(size_t)brow * NH + gcol] = hv[r];
            }
        } else {
            accx = xpart(t + 1);
        }
    }
}

// ---------------------------------------------------------------------------
// Readout: Y[32768,128] = HL[32768,1024](f32->f16) @ Wo^T(f16), fp32 out.
__global__ __launch_bounds__(256, 4) void ygemm_kernel(
    const float* __restrict__ HL, const unsigned short* __restrict__ Wo,
    float* __restrict__ Y)
{
    const int tid = threadIdx.x;
    const int wave = tid >> 6, lane = tid & 63;
    const int l15 = lane & 15, lk = lane >> 4;
    const size_t rowbase = (size_t)blockIdx.x * 64;

    f32x4 acc[4][2] = {};

    #pragma unroll 2
    for (int ki = 0; ki < 32; ++ki) {
        const int k0 = ki * 32 + lk * 8;
        half8 bfr[2];
        #pragma unroll
        for (int nt = 0; nt < 2; ++nt) {
            int ncol = (wave * 2 + nt) * 16 + l15;
            ushort8 braw = *(const ushort8*)(Wo + ncol * NH + k0);
            bfr[nt] = __builtin_bit_cast(half8, braw);
        }
        #pragma unroll
        for (int mt = 0; mt < 4; ++mt) {
            size_t row = rowbase + mt * 16 + l15;
            const float4* ap = (const float4*)(HL + row * NH + k0);
            float4 a0 = ap[0];
            float4 a1 = ap[1];
            half8 a = { (_Float16)a0.x, (_Float16)a0.y, (_Float16)a0.z, (_Float16)a0.w,
                        (_Float16)a1.x, (_Float16)a1.y, (_Float16)a1.z, (_Float16)a1.w };
            #pragma unroll
            for (int nt = 0; nt < 2; ++nt)
                acc[mt][nt] = __builtin_amdgcn_mfma_f32_16x16x32_f16(a, bfr[nt], acc[mt][nt], 0, 0, 0);
        }
    }

    #pragma unroll
    for (int mt = 0; mt < 4; ++mt) {
        #pragma unroll
        for (int nt = 0; nt < 2; ++nt) {
            int ncol = (wave * 2 + nt) * 16 + l15;
            #pragma unroll
            for (int r = 0; r < 4; ++r) {
                size_t row = rowbase + mt * 16 + lk * 4 + r;
                Y[row * NIN + ncol] = acc[mt][nt][r];
            }
        }
    }
}

// ---------------------------------------------------------------------------
extern "C" void kernel_launch(void* const* d_in, const int* in_sizes, int n_in,
                              void* d_out, int out_size, void* d_ws, size_t ws_size,
                              hipStream_t stream)
{
    const float* X      = (const float*)d_in[0];
    const float* hidden = (const float*)d_in[1];
    const float* W_in   = (const float*)d_in[2];
    const float* W_hh   = (const float*)d_in[3];
    const float* b_hh   = (const float*)d_in[4];
    const float* W_out  = (const float*)d_in[5];
    const float* alpha  = (const float*)d_in[6];
    const float* noise  = (const float*)d_in[7];

    char* ws = (char*)d_ws;   // ~10.2 MB
    unsigned short* Xt = (unsigned short*)(ws + OFF_XT);
    float*          NB = (float*)(ws + OFF_NB);
    unsigned short* Wo = (unsigned short*)(ws + OFF_WO);
    unsigned int*  Hb0 = (unsigned int*)(ws + OFF_HB);
    unsigned int*  Hb1 = Hb0 + (size_t)B_ * NH / 2;

    float* hidden_list = (float*)d_out;                                  // [128,256,1024]
    float* output_list = hidden_list + (size_t)B_ * T_ * NH;             // [128,256,128]
    float* h_final     = output_list + (size_t)B_ * T_ * NIN;            // [128,1024]

    setup_kernel<<<(B_ * T_ * NIN + 255) / 256, 256, 0, stream>>>(
        X, hidden, b_hh, W_out, alpha, noise, Xt, NB, Wo, Hb0, Hb1);

    rnn_step_kernel<<<GM * GN, 256, 0, stream>>>(
        W_hh, W_in, Xt, NB, Hb0, Hb1, hidden_list, h_final);

    ygemm_kernel<<<(B_ * T_) / 64, 256, 0, stream>>>(
        hidden_list, Wo, output_list);
}